// Round 8
// baseline (5342.738 us; speedup 1.0000x reference)
//
#include <hip/hip_runtime.h>
#include <math.h>

#define TT 8192
#define KK 24
#define UU 104
#define NEGINF (-1e18f)
#define INV_LN2 1.4426950408889634f
#define CLMP 60.0f

__device__ __forceinline__ float exp2_(float x) {
#if __has_builtin(__builtin_amdgcn_exp2f)
  return __builtin_amdgcn_exp2f(x);
#else
  return exp2f(x);
#endif
}

// Barrier that drains ONLY LDS (lgkmcnt), not global loads (vmcnt).
__device__ __forceinline__ void wg_barrier() {
  asm volatile("s_waitcnt lgkmcnt(0)" ::: "memory");
  __builtin_amdgcn_s_barrier();
  asm volatile("" ::: "memory");
}

template<int CTRL>
__device__ __forceinline__ float dppf(float x) {
  return __builtin_bit_cast(float,
    __builtin_amdgcn_update_dpp(0, __builtin_bit_cast(int, x), CTRL, 0xF, 0xF, true));
}
// 16-lane-row sum reduction via DPP (VALU only), broadcast to all 16 lanes
__device__ __forceinline__ float red16_sum(float v) {
  v += dppf<0xB1>(v);   // quad_perm xor1
  v += dppf<0x4E>(v);   // quad_perm xor2
  v += dppf<0x124>(v);  // row_ror:4
  v += dppf<0x128>(v);  // row_ror:8
  return v;
}
// dst[L] = src[(L-1)&15]
__device__ __forceinline__ float ror1(float x) { return dppf<0x121>(x); }

// shared producer/consumer init expressions (must be bitwise identical)
__device__ __forceinline__ float a0_of(const float* lp, const float* lD,
                                       const float* em, int s) {
  return (lp[s] * INV_LN2 + lD[s * UU] * INV_LN2) + em[s] * INV_LN2;
}
__device__ __forceinline__ float nh0_of(const float* lD, const float* cum, int s) {
  return lD[s * UU] * INV_LN2 + cum[(size_t)TT * KK + s];
}

// cum[t][k] = (1/ln2) * sum_{s<t} em[s][k]*qw[s],  t = 0..TT  (row-major [TT+1][KK])
__global__ __launch_bounds__(256) void cumsum_kernel(
    const float* __restrict__ em, const float* __restrict__ qw,
    float* __restrict__ cum)
{
  const int k = blockIdx.x;
  const int tid = threadIdx.x;
  const int lane = tid & 63;
  const int wid = tid >> 6;
  __shared__ float wsum[4];
  float carry = 0.0f;
  if (tid == 0) cum[k] = 0.0f;
  for (int c = 0; c < TT / 256; ++c) {
    int t = c * 256 + tid;
    float v = em[t * KK + k] * (qw[t] * INV_LN2);
    #pragma unroll
    for (int d = 1; d < 64; d <<= 1) {
      float tmp = __shfl_up(v, d);
      if (lane >= d) v += tmp;
    }
    if (lane == 63) wsum[wid] = v;
    __syncthreads();
    float off = carry;
    #pragma unroll
    for (int w = 0; w < 4; ++w)
      if (w < wid) off += wsum[w];
    cum[(size_t)(t + 1) * KK + k] = off + v;
    carry += wsum[0] + wsum[1] + wsum[2] + wsum[3];
    __syncthreads();
  }
}

// ONE block, 768 threads on ONE CU: waves 0-5 forward, waves 6-11 backward.
// The two independent scans interleave on the same SIMDs so each direction's
// chain/LDS stalls are filled by the other's instruction issue.
// Numerics identical to the round-6 passing kernel.
__global__ __launch_bounds__(768, 1) void scan_kernel(
    const float* __restrict__ em,
    const float* __restrict__ log_pi,
    const float* __restrict__ log_A,
    const float* __restrict__ log_D,
    const float* __restrict__ cum,
    float* __restrict__ alpha_out,
    float* __restrict__ beta_out)
{
  __shared__ __align__(16) float xbF[2][32];
  __shared__ __align__(16) float xbB[2][32];
  const int tid = threadIdx.x;
  const bool isF = (tid < 384);
  const int lt = isF ? tid : (tid - 384);
  const int g = lt >> 4;           // state 0..23
  const int L = lt & 15;           // lane in group
  const bool l0 = (L == 0);
  const int j1 = 2 * L, j2 = 2 * L + 1;
  const bool vj = (j1 < KK);       // pairs are both-valid or both-invalid
  const int jc = vj ? j1 : 0;

  // log_D[g][u] (log2), u = L + 16*i
  float ld0 = log_D[g * UU + L] * INV_LN2;
  float ld1 = log_D[g * UU + L + 16] * INV_LN2;
  float ld2 = log_D[g * UU + L + 32] * INV_LN2;
  float ld3 = log_D[g * UU + L + 48] * INV_LN2;
  float ld4 = log_D[g * UU + L + 64] * INV_LN2;
  float ld5 = log_D[g * UU + L + 80] * INV_LN2;
  float ld6 = (L < 8) ? log_D[g * UU + L + 96] * INV_LN2 : NEGINF;
  float d0 = log_D[g * UU] * INV_LN2;

  if (isF) {
    // ---------------- forward ----------------
    if (lt < 8) { xbF[0][24 + lt] = 1.0f; xbF[1][24 + lt] = 1.0f; }
    float Ak1 = (vj && j1 != g) ? log_A[j1 * KK + g] * INV_LN2 : NEGINF;
    float Ak2 = (vj && j2 != g) ? log_A[j2 * KK + g] * INV_LN2 : NEGINF;
    float lpi2 = log_pi[g] * INV_LN2;
    float a0 = a0_of(log_pi, log_D, em, g);
    float cc0 = cum[1 * KK + g], cc1 = cum[2 * KK + g],
          cc2 = cum[3 * KK + g], cc3 = cum[4 * KK + g];
    float2 pj1r = *(const float2*)&cum[1 * KK + jc];
    float2 pjA = *(const float2*)&cum[2 * KK + jc];
    float2 pjB = *(const float2*)&cum[3 * KK + jc];
    float2 pjC = *(const float2*)&cum[4 * KK + jc];
    float Ua = a0 - cc0;                         // Ua(0), group frame
    float Uaj1 = vj ? (a0_of(log_pi, log_D, em, j1) - pj1r.x) : 0.f;
    float Uaj2 = vj ? (a0_of(log_pi, log_D, em, j2) - pj1r.y) : 0.f;
    float Mh = a0;                               // gamma anchor
    float f1 = exp2_(fminf((pj1r.x + Uaj1) + (Ak1 - Mh), CLMP));
    float f2 = exp2_(fminf((pj1r.y + Uaj2) + (Ak2 - Mh), CLMP));
    float fc = exp2_(fminf((Mh + d0) - (cc0 + Ua), CLMP));
    float fc0 = l0 ? fc : 0.f;
    // window: phi[0]=log_pi at lane0 slot, rotate into step-1 position
    float P0 = l0 ? lpi2 : NEGINF;
    float P1 = NEGINF, P2 = NEGINF, P3 = NEGINF,
          P4 = NEGINF, P5 = NEGINF, P6 = NEGINF;
    {
      float r0 = ror1(P0), r1 = ror1(P1), r2 = ror1(P2), r3 = ror1(P3),
            r4 = ror1(P4), r5 = ror1(P5), r6 = ror1(P6);
      P0 = r0;
      P1 = l0 ? r0 : r1;  P2 = l0 ? r1 : r2;  P3 = l0 ? r2 : r3;
      P4 = l0 ? r3 : r4;  P5 = l0 ? r4 : r5;  P6 = l0 ? r5 : r6;
    }
    float mU = 0.f - Ua;
    float e0 = exp2_(P0 + (ld0 + mU));
    float e1 = exp2_(P1 + (ld1 + mU));
    float e2 = exp2_(P2 + (ld2 + mU));
    float e3 = exp2_(P3 + (ld3 + mU));
    float e4 = exp2_(P4 + (ld4 + mU));
    float e5 = exp2_(P5 + (ld5 + mU));
    float e6 = exp2_(P6 + (ld6 + mU));
    float sloc = (((l0 ? 0.f : e0) + e1) + (e2 + e3)) + ((e4 + e5) + e6);
    if (l0) alpha_out[g] = a0;
    float2 Sjr; Sjr.x = 1.0f; Sjr.y = 1.0f;      // S(0) == 1 for all states
    __syncthreads();
    #pragma unroll 1
    for (int t = 1; t < TT; ++t) {
      // ---- critical chain ----
      float w  = fmaf(Sjr.x, f1, Sjr.y * f2);
      float sG = red16_sum(w);                   // 2^(gamma[t]-Mh)
      float vv = fmaf(sG, fc0, sloc);            // u=0 folded in linearly
      float S  = red16_sum(vv);
      float Sp = fmaxf(S, 1e-37f);
      if (l0) xbF[t & 1][g] = Sp;
      wg_barrier();
      float2 Sjn = *(const float2*)&xbF[t & 1][j1];   // next operand (issue early)
      // ---- prefetch ----
      int tp = (t + 4 <= TT) ? (t + 4) : TT;
      float ccN = cum[(size_t)tp * KK + g];
      float2 pjN = *(const float2*)&cum[(size_t)tp * KK + jc];
      // ---- tail (off critical path) ----
      float lgG = __log2f(fmaxf(sG, 1e-37f));
      float lgS = __log2f(Sp);
      Mh += lgG;                                 // gamma[t]
      float phi = Mh - cc0;                      // phi[t]
      if (l0) alpha_out[(size_t)t * KK + g] = (cc1 + Ua) + lgS;
      Ua += lgS;                                 // Ua(t)
      Uaj1 += __log2f(Sjr.x);                    // -> Ua_j(t-1), bitwise == producer
      Uaj2 += __log2f(Sjr.y);
      f1 = exp2_(fminf((pjA.x + Uaj1) + (Ak1 - Mh), CLMP));
      f2 = exp2_(fminf((pjA.y + Uaj2) + (Ak2 - Mh), CLMP));
      fc = exp2_(fminf((Mh + d0) - (cc1 + Ua), CLMP));
      fc0 = l0 ? fc : 0.f;
      // window: insert phi[t] at lane0 then rotate (prep step t+1)
      float P0i = l0 ? phi : P0;
      float r0 = ror1(P0i), r1 = ror1(P1), r2 = ror1(P2), r3 = ror1(P3),
            r4 = ror1(P4), r5 = ror1(P5), r6 = ror1(P6);
      P0 = r0;
      P1 = l0 ? r0 : r1;  P2 = l0 ? r1 : r2;  P3 = l0 ? r2 : r3;
      P4 = l0 ? r3 : r4;  P5 = l0 ? r4 : r5;  P6 = l0 ? r5 : r6;
      float mU2 = 0.f - Ua;
      e0 = exp2_(P0 + (ld0 + mU2));
      e1 = exp2_(P1 + (ld1 + mU2));
      e2 = exp2_(P2 + (ld2 + mU2));
      e3 = exp2_(P3 + (ld3 + mU2));
      e4 = exp2_(P4 + (ld4 + mU2));
      e5 = exp2_(P5 + (ld5 + mU2));
      e6 = exp2_(P6 + (ld6 + mU2));
      sloc = (((l0 ? 0.f : e0) + e1) + (e2 + e3)) + ((e4 + e5) + e6);
      Sjr = Sjn;
      cc0 = cc1; cc1 = cc2; cc2 = cc3; cc3 = ccN;
      pjA = pjB; pjB = pjC; pjC = pjN;
    }
  } else {
    // ---------------- backward ----------------
    if (lt < 8) { xbB[0][24 + lt] = 1.0f; xbB[1][24 + lt] = 1.0f; }
    float Cj1 = (vj && j1 != g) ? log_A[g * KK + j1] * INV_LN2 : NEGINF;
    float Cj2 = (vj && j2 != g) ? log_A[g * KK + j2] * INV_LN2 : NEGINF;
    float cT = cum[(size_t)TT * KK + g];
    float cA = cum[(size_t)(TT - 1) * KK + g];
    float cB = cum[(size_t)(TT - 2) * KK + g];
    float cC = cum[(size_t)(TT - 3) * KK + g];
    float2 pj1b = *(const float2*)&cum[(size_t)(TT - 1) * KK + jc];
    float2 pjB = *(const float2*)&cum[(size_t)(TT - 2) * KK + jc];
    float2 pjC = *(const float2*)&cum[(size_t)(TT - 3) * KK + jc];
    float Nh = nh0_of(log_D, cum, g);            // n-anchor = d0 + cum[T]
    float Nhj1 = vj ? nh0_of(log_D, cum, j1) : 0.f;
    float Nhj2 = vj ? nh0_of(log_D, cum, j2) : 0.f;
    float bh = 0.0f;                             // beta[TT-1] = 0
    float f1 = exp2_(fminf((Nhj1 - pj1b.x) + Cj1, CLMP));
    float f2 = exp2_(fminf((Nhj2 - pj1b.y) + Cj2, CLMP));
    // window for step TT-2: lane L = psi[TT-1+L]; only lane0 valid (= cum[T])
    float Q0 = l0 ? cT : NEGINF;
    float Q1 = NEGINF, Q2 = NEGINF, Q3 = NEGINF,
          Q4 = NEGINF, Q5 = NEGINF, Q6 = NEGINF;
    float mN = 0.f - Nh;
    float e0 = exp2_(Q0 + (ld0 + mN));
    float e1 = exp2_(Q1 + (ld1 + mN));
    float e2 = exp2_(Q2 + (ld2 + mN));
    float e3 = exp2_(Q3 + (ld3 + mN));
    float e4 = exp2_(Q4 + (ld4 + mN));
    float e5 = exp2_(Q5 + (ld5 + mN));
    float e6 = exp2_(Q6 + (ld6 + mN));
    float slocB = ((e0 + e1) + (e2 + e3)) + ((e4 + e5) + e6);  // incl. lane0
    float fb = 0.f, fb0 = 0.f, sBprev = 0.f;
    float psi_prev = cT;                          // psi[TT-1]
    if (l0) beta_out[(size_t)(TT - 1) * KK + g] = 0.0f;
    __syncthreads();
    #pragma unroll 1
    for (int t = TT - 2; t >= 0; --t) {
      // ---- critical: phase A (window LSE) ----
      float vA = fmaf(sBprev, fb0, slocB);
      float SA = red16_sum(vA);
      float SAp = fmaxf(SA, 1e-37f);
      if (l0) xbB[t & 1][g] = SAp;
      wg_barrier();
      float2 SAj = *(const float2*)&xbB[t & 1][j1];
      // ---- prefetch ----
      int tm = (t - 2 >= 0) ? (t - 2) : 0;
      float cN = cum[(size_t)tm * KK + g];
      float2 pjN = *(const float2*)&cum[(size_t)tm * KK + jc];
      // ---- critical: phase B (beta mix) ----
      float wb = fmaf(SAj.x, f1, SAj.y * f2);
      float sB = red16_sum(wb);                  // 2^(beta[t]-bh)
      // ---- tail (off critical path) ----
      float lgA = __log2f(SAp);
      float lgB = __log2f(fmaxf(sB, 1e-37f));
      Nh += lgA;                                 // n(t)
      float bt = bh + lgB;                       // beta[t]
      if (l0) beta_out[(size_t)t * KK + g] = bt;
      fb = exp2_(fminf(((d0 + cA) + bh) - Nh, CLMP));  // uses OLD bh
      fb0 = l0 ? fb : 0.f;
      bh = bt;
      Nhj1 += __log2f(SAj.x);                    // -> Nh_j(t), bitwise == producer
      Nhj2 += __log2f(SAj.y);
      f1 = exp2_(fminf((Nhj1 - pjB.x) + (Cj1 - bh), CLMP));
      f2 = exp2_(fminf((Nhj2 - pjB.y) + (Cj2 - bh), CLMP));
      // window: fill lane0 slot with psi[t+1], rotate (prep step t-1)
      float Q0i = l0 ? psi_prev : Q0;
      float r0 = ror1(Q0i), r1 = ror1(Q1), r2 = ror1(Q2), r3 = ror1(Q3),
            r4 = ror1(Q4), r5 = ror1(Q5), r6 = ror1(Q6);
      Q0 = r0;
      Q1 = l0 ? r0 : r1;  Q2 = l0 ? r1 : r2;  Q3 = l0 ? r2 : r3;
      Q4 = l0 ? r3 : r4;  Q5 = l0 ? r4 : r5;  Q6 = l0 ? r5 : r6;
      psi_prev = cA + bt;                        // psi[t]
      float mN2 = 0.f - Nh;
      e0 = exp2_(Q0 + (ld0 + mN2));
      e1 = exp2_(Q1 + (ld1 + mN2));
      e2 = exp2_(Q2 + (ld2 + mN2));
      e3 = exp2_(Q3 + (ld3 + mN2));
      e4 = exp2_(Q4 + (ld4 + mN2));
      e5 = exp2_(Q5 + (ld5 + mN2));
      e6 = exp2_(Q6 + (ld6 + mN2));
      slocB = (((l0 ? 0.f : e0) + e1) + (e2 + e3)) + ((e4 + e5) + e6);
      sBprev = sB;
      cA = cB; cB = cC; cC = cN;
      pjB = pjC; pjC = pjN;
    }
  }
}

// out = softmax over k of (alpha2 + beta2), log2 domain (ratios identical)
__global__ __launch_bounds__(256) void softmax_kernel(
    float* __restrict__ ab, const float* __restrict__ beta)
{
  int t = blockIdx.x * 256 + threadIdx.x;
  float s[KK];
  float mx = -INFINITY;
  #pragma unroll
  for (int k = 0; k < KK; ++k) {
    s[k] = ab[(size_t)t * KK + k] + beta[(size_t)t * KK + k];
    mx = fmaxf(mx, s[k]);
  }
  float sum = 0.0f;
  #pragma unroll
  for (int k = 0; k < KK; ++k) { s[k] = exp2_(s[k] - mx); sum += s[k]; }
  float inv = 1.0f / sum;
  #pragma unroll
  for (int k = 0; k < KK; ++k) ab[(size_t)t * KK + k] = s[k] * inv;
}

extern "C" void kernel_launch(void* const* d_in, const int* in_sizes, int n_in,
                              void* d_out, int out_size, void* d_ws, size_t ws_size,
                              hipStream_t stream) {
  const float* em  = (const float*)d_in[0];   // (T,K)
  const float* qw  = (const float*)d_in[1];   // (T,)
  const float* lpi = (const float*)d_in[2];   // (K,)
  const float* lA  = (const float*)d_in[3];   // (K,K)
  const float* lD  = (const float*)d_in[4];   // (K,U)
  // d_in[5] transition_mask == 1-eye(K): applied analytically (j != k)

  float* out  = (float*)d_out;                 // alpha2, then softmax in place
  float* cum  = (float*)d_ws;                  // (T+1)*K floats
  float* beta = (float*)d_ws + (size_t)(TT + 1) * KK;  // T*K floats

  cumsum_kernel<<<KK, 256, 0, stream>>>(em, qw, cum);
  scan_kernel<<<1, 768, 0, stream>>>(em, lpi, lA, lD, cum, out, beta);
  softmax_kernel<<<TT / 256, 256, 0, stream>>>(out, beta);
}

// Round 10
// 3562.254 us; speedup vs baseline: 1.4998x; 1.4998x over previous
//
#include <hip/hip_runtime.h>
#include <math.h>

#define TT 8192
#define KK 24
#define UU 104
#define NEGINF (-1e18f)
#define INV_LN2 1.4426950408889634f
#define CLMP 60.0f

__device__ __forceinline__ float exp2_(float x) {
#if __has_builtin(__builtin_amdgcn_exp2f)
  return __builtin_amdgcn_exp2f(x);
#else
  return exp2f(x);
#endif
}

// Barrier draining only LDS (lgkmcnt), not global loads.
__device__ __forceinline__ void wg_barrier() {
  asm volatile("s_waitcnt lgkmcnt(0)" ::: "memory");
  __builtin_amdgcn_s_barrier();
  asm volatile("" ::: "memory");
}

template<int CTRL>
__device__ __forceinline__ float dppf(float x) {
  return __builtin_bit_cast(float,
    __builtin_amdgcn_update_dpp(0, __builtin_bit_cast(int, x), CTRL, 0xF, 0xF, true));
}
// 8-lane (octet) sum reduction: quad xor1, quad xor2, then half-row mirror
// (after the two quad levels every lane holds its quad sum; half-row mirror
// pairs each lane with the other quad of the octet). Result in all 8 lanes.
__device__ __forceinline__ float red8_sum(float v) {
  v += dppf<0xB1>(v);    // quad_perm [1,0,3,2]  (xor 1)
  v += dppf<0x4E>(v);    // quad_perm [2,3,0,1]  (xor 2)
  v += dppf<0x141>(v);   // row_half_mirror: lane l <-> 7-l within each octet
  return v;
}
// dst[l] = src[(l-1)&15] ; dst[l] = src[(l-9)&15]
__device__ __forceinline__ float ror1(float x) { return dppf<0x121>(x); }
__device__ __forceinline__ float ror9(float x) { return dppf<0x129>(x); }

// cum[t][k] = (1/ln2) * sum_{s<t} em[s][k]*qw[s],  t = 0..TT  ([TT+1][KK])
__global__ __launch_bounds__(256) void cumsum_kernel(
    const float* __restrict__ em, const float* __restrict__ qw,
    float* __restrict__ cum)
{
  const int k = blockIdx.x;
  const int tid = threadIdx.x;
  const int lane = tid & 63;
  const int wid = tid >> 6;
  __shared__ float wsum[4];
  float carry = 0.0f;
  if (tid == 0) cum[k] = 0.0f;
  for (int c = 0; c < TT / 256; ++c) {
    int t = c * 256 + tid;
    float v = em[t * KK + k] * (qw[t] * INV_LN2);
    #pragma unroll
    for (int d = 1; d < 64; d <<= 1) {
      float tmp = __shfl_up(v, d);
      if (lane >= d) v += tmp;
    }
    if (lane == 63) wsum[wid] = v;
    __syncthreads();
    float off = carry;
    #pragma unroll
    for (int w = 0; w < 4; ++w)
      if (w < wid) off += wsum[w];
    cum[(size_t)(t + 1) * KK + k] = off + v;
    carry += wsum[0] + wsum[1] + wsum[2] + wsum[3];
    __syncthreads();
  }
}

// block 0: forward -> alpha_out ; block 1: backward -> beta_out
// 24 states x 8 lanes = 192 threads = 3 waves (<=1 wave/SIMD).
// Log-domain, per-state anchors (r2-proven numerics). Window: 13 slots/lane,
// u = L + 8*i, shifted with ror1/ror9 DPP; u=0 term on-chain via sG*fc0.
// Mix: lane L reads float4 of published log-values (xbuf padded to 32).
__global__ __launch_bounds__(192, 1) void scan_kernel(
    const float* __restrict__ em,
    const float* __restrict__ log_pi,
    const float* __restrict__ log_A,
    const float* __restrict__ log_D,
    const float* __restrict__ cum,
    float* __restrict__ alpha_out,
    float* __restrict__ beta_out)
{
  __shared__ __align__(16) float xb[2][32];
  const int tid = threadIdx.x;
  const int g = tid >> 3;          // state 0..23
  const int L = tid & 7;           // lane in 8-lane group
  const bool l0 = (L == 0);

  if (tid < 8) { xb[0][24 + tid] = 0.0f; xb[1][24 + tid] = 0.0f; }

  // mix j-assignment: lane L handles j = 4L .. 4L+3 (L<6); L=6,7 idle in mix
  const int jb = 4 * L;
  float Ak0, Ak1, Ak2, Ak3;        // set per direction below
  float d0 = log_D[g * UU] * INV_LN2;

  if (blockIdx.x == 0) {
    // ---------------- forward ----------------
    // window ld table: slot s = L + 8i  <->  u = s+1  -> ld[s+1]
    float LD[13];
    #pragma unroll
    for (int i = 0; i < 13; ++i) {
      int u = L + 8 * i + 1;
      LD[i] = (u <= 103) ? log_D[g * UU + u] * INV_LN2 : NEGINF;
    }
    Ak0 = (jb + 0 < KK && jb + 0 != g) ? log_A[(jb + 0) * KK + g] * INV_LN2 : NEGINF;
    Ak1 = (jb + 1 < KK && jb + 1 != g) ? log_A[(jb + 1) * KK + g] * INV_LN2 : NEGINF;
    Ak2 = (jb + 2 < KK && jb + 2 != g) ? log_A[(jb + 2) * KK + g] * INV_LN2 : NEGINF;
    Ak3 = (jb + 3 < KK && jb + 3 != g) ? log_A[(jb + 3) * KK + g] * INV_LN2 : NEGINF;

    float lpi2 = log_pi[g] * INV_LN2;
    float a0 = (lpi2 + d0) + em[g] * INV_LN2;
    if (l0) { xb[0][g] = a0; alpha_out[g] = a0; }
    float Mh = a0;                              // gamma anchor (per state)
    float cc0 = cum[1 * KK + g], cc1 = cum[2 * KK + g],
          cc2 = cum[3 * KK + g], cc3 = cum[4 * KK + g];
    float Ua = a0 - cc0;                        // alpha-cum anchor (per state)
    // window init (entering step 1): slot s holds phi[0 - s]; only s=0 valid
    float P0 = (tid % 8 == 0 && true) ? 0.0f : 0.0f;  // placeholder init below
    float P1, P2, P3, P4, P5, P6, P7, P8, P9, P10, P11, P12;
    P0 = l0 ? lpi2 : NEGINF;                    // phi[0] = log_pi
    P1 = P2 = P3 = P4 = P5 = P6 = P7 = P8 = P9 = P10 = P11 = P12 = NEGINF;
    float mUa = 0.f - Ua;
    float sloc;
    {
      float e0  = exp2_(P0  + (LD[0]  + mUa));
      float e1  = exp2_(P1  + (LD[1]  + mUa));
      float e2  = exp2_(P2  + (LD[2]  + mUa));
      float e3  = exp2_(P3  + (LD[3]  + mUa));
      float e4  = exp2_(P4  + (LD[4]  + mUa));
      float e5  = exp2_(P5  + (LD[5]  + mUa));
      float e6  = exp2_(P6  + (LD[6]  + mUa));
      float e7  = exp2_(P7  + (LD[7]  + mUa));
      float e8  = exp2_(P8  + (LD[8]  + mUa));
      float e9  = exp2_(P9  + (LD[9]  + mUa));
      float e10 = exp2_(P10 + (LD[10] + mUa));
      float e11 = exp2_(P11 + (LD[11] + mUa));
      float e12 = exp2_(P12 + (LD[12] + mUa));
      sloc = (((e0 + e1) + (e2 + e3)) + ((e4 + e5) + (e6 + e7))) +
             (((e8 + e9) + (e10 + e11)) + e12);
    }
    float Akm0 = Ak0 - Mh, Akm1 = Ak1 - Mh, Akm2 = Ak2 - Mh, Akm3 = Ak3 - Mh;
    float fc0 = l0 ? exp2_(fminf((Mh + d0) - (cc0 + Ua), CLMP)) : 0.0f;
    __syncthreads();
    #pragma unroll 1
    for (int t = 1; t < TT; ++t) {
      float4 S4 = *(const float4*)&xb[(t - 1) & 1][jb];
      int tp = (t + 4 <= TT) ? (t + 4) : TT;
      float ccN = cum[(size_t)tp * KK + g];
      // ---- critical chain ----
      float w0 = S4.x + Akm0, w1 = S4.y + Akm1,
            w2 = S4.z + Akm2, w3 = S4.w + Akm3;
      float sG = red8_sum((exp2_(w0) + exp2_(w1)) + (exp2_(w2) + exp2_(w3)));
      float vv = fmaf(sG, fc0, sloc);           // u=0 term folded at lane 0
      float S  = red8_sum(vv);
      float Sp = fmaxf(S, 1e-37f);
      float lgS = __log2f(Sp);
      float a = (cc1 + Ua) + lgS;               // alpha[t]
      if (l0) xb[t & 1][g] = a;
      wg_barrier();
      if (l0) alpha_out[(size_t)t * KK + g] = a;
      // ---- tail (off the cross-step recursion) ----
      float lgG = __log2f(fmaxf(sG, 1e-37f));
      float gamma = Mh + lgG;
      Mh = gamma;
      float phi = gamma - cc0;
      Ua += lgS;
      Akm0 = Ak0 - Mh; Akm1 = Ak1 - Mh; Akm2 = Ak2 - Mh; Akm3 = Ak3 - Mh;
      fc0 = l0 ? exp2_(fminf((Mh + d0) - (cc1 + Ua), CLMP)) : 0.0f;
      // window shift: slot s new = old slot s-1 ; fresh phi -> slot 0 @ L==0
      float r0 = ror1(P0),  r1 = ror1(P1),  r2 = ror1(P2),  r3 = ror1(P3),
            r4 = ror1(P4),  r5 = ror1(P5),  r6 = ror1(P6),  r7 = ror1(P7),
            r8 = ror1(P8),  r9 = ror1(P9),  r10 = ror1(P10), r11 = ror1(P11),
            r12 = ror1(P12);
      float q1 = ror9(P0),  q2 = ror9(P1),  q3 = ror9(P2),  q4 = ror9(P3),
            q5 = ror9(P4),  q6 = ror9(P5),  q7 = ror9(P6),  q8 = ror9(P7),
            q9 = ror9(P8),  q10 = ror9(P9), q11 = ror9(P10), q12 = ror9(P11);
      P0  = l0 ? phi : r0;
      P1  = l0 ? q1  : r1;   P2  = l0 ? q2  : r2;
      P3  = l0 ? q3  : r3;   P4  = l0 ? q4  : r4;
      P5  = l0 ? q5  : r5;   P6  = l0 ? q6  : r6;
      P7  = l0 ? q7  : r7;   P8  = l0 ? q8  : r8;
      P9  = l0 ? q9  : r9;   P10 = l0 ? q10 : r10;
      P11 = l0 ? q11 : r11;  P12 = l0 ? q12 : r12;
      float mU = 0.f - Ua;
      float e0  = exp2_(P0  + (LD[0]  + mU));
      float e1  = exp2_(P1  + (LD[1]  + mU));
      float e2  = exp2_(P2  + (LD[2]  + mU));
      float e3  = exp2_(P3  + (LD[3]  + mU));
      float e4  = exp2_(P4  + (LD[4]  + mU));
      float e5  = exp2_(P5  + (LD[5]  + mU));
      float e6  = exp2_(P6  + (LD[6]  + mU));
      float e7  = exp2_(P7  + (LD[7]  + mU));
      float e8  = exp2_(P8  + (LD[8]  + mU));
      float e9  = exp2_(P9  + (LD[9]  + mU));
      float e10 = exp2_(P10 + (LD[10] + mU));
      float e11 = exp2_(P11 + (LD[11] + mU));
      float e12 = exp2_(P12 + (LD[12] + mU));
      sloc = (((e0 + e1) + (e2 + e3)) + ((e4 + e5) + (e6 + e7))) +
             (((e8 + e9) + (e10 + e11)) + e12);
      cc0 = cc1; cc1 = cc2; cc2 = cc3; cc3 = ccN;
    }
  } else {
    // ---------------- backward ----------------
    // window ld table: slot s = L + 8i  <->  u = s  -> ld[s]  (all valid)
    float LD[13];
    #pragma unroll
    for (int i = 0; i < 13; ++i)
      LD[i] = log_D[g * UU + (L + 8 * i)] * INV_LN2;
    Ak0 = (jb + 0 < KK && jb + 0 != g) ? log_A[g * KK + (jb + 0)] * INV_LN2 : NEGINF;
    Ak1 = (jb + 1 < KK && jb + 1 != g) ? log_A[g * KK + (jb + 1)] * INV_LN2 : NEGINF;
    Ak2 = (jb + 2 < KK && jb + 2 != g) ? log_A[g * KK + (jb + 2)] * INV_LN2 : NEGINF;
    Ak3 = (jb + 3 < KK && jb + 3 != g) ? log_A[g * KK + (jb + 3)] * INV_LN2 : NEGINF;

    float cT = cum[(size_t)TT * KK + g];
    if (l0) beta_out[(size_t)(TT - 1) * KK + g] = 0.0f;
    float Nh = cT + d0;                         // n anchor (per state)
    float bh = 0.0f;                            // beta anchor (per state)
    float cA = cum[(size_t)(TT - 1) * KK + g];  // cum[t+1] for t = TT-2
    float cB = cum[(size_t)(TT - 2) * KK + g];
    float cC = cum[(size_t)(TT - 3) * KK + g];
    // window entering step TT-2: slot s holds psi[TT-1+s]; only s=0 valid
    float Q0 = l0 ? cT : NEGINF;                // psi[TT-1] = cum[TT]
    float Q1 = NEGINF, Q2 = NEGINF, Q3 = NEGINF, Q4 = NEGINF, Q5 = NEGINF,
          Q6 = NEGINF, Q7 = NEGINF, Q8 = NEGINF, Q9 = NEGINF, Q10 = NEGINF,
          Q11 = NEGINF, Q12 = NEGINF;
    float slocB;
    {
      float mN = 0.f - Nh;
      float e0  = exp2_(Q0  + (LD[0]  + mN));
      float e1  = exp2_(Q1  + (LD[1]  + mN));
      float e2  = exp2_(Q2  + (LD[2]  + mN));
      float e3  = exp2_(Q3  + (LD[3]  + mN));
      float e4  = exp2_(Q4  + (LD[4]  + mN));
      float e5  = exp2_(Q5  + (LD[5]  + mN));
      float e6  = exp2_(Q6  + (LD[6]  + mN));
      float e7  = exp2_(Q7  + (LD[7]  + mN));
      float e8  = exp2_(Q8  + (LD[8]  + mN));
      float e9  = exp2_(Q9  + (LD[9]  + mN));
      float e10 = exp2_(Q10 + (LD[10] + mN));
      float e11 = exp2_(Q11 + (LD[11] + mN));
      float e12 = exp2_(Q12 + (LD[12] + mN));
      slocB = (((e0 + e1) + (e2 + e3)) + ((e4 + e5) + (e6 + e7))) +
              (((e8 + e9) + (e10 + e11)) + e12);
    }
    float Cm0 = Ak0 - bh, Cm1 = Ak1 - bh, Cm2 = Ak2 - bh, Cm3 = Ak3 - bh;
    __syncthreads();
    #pragma unroll 1
    for (int t = TT - 2; t >= 0; --t) {
      // ---- phase A: window LSE -> m[t] ----
      float SA = red8_sum(slocB);
      float SAp = fmaxf(SA, 1e-37f);
      float lgA = __log2f(SAp);
      float n = Nh + lgA;
      float m = n - cA;                         // m[t] (log)
      if (l0) xb[t & 1][g] = m;
      wg_barrier();
      float4 m4 = *(const float4*)&xb[t & 1][jb];
      int tm = (t - 2 >= 0) ? (t - 2) : 0;
      float cN = cum[(size_t)tm * KK + g];
      // ---- phase B: beta mix ----
      float y0 = m4.x + Cm0, y1 = m4.y + Cm1,
            y2 = m4.z + Cm2, y3 = m4.w + Cm3;
      float sB = red8_sum((exp2_(y0) + exp2_(y1)) + (exp2_(y2) + exp2_(y3)));
      float lgB = __log2f(fmaxf(sB, 1e-37f));
      float bt = bh + lgB;                      // beta[t]
      if (l0) beta_out[(size_t)t * KK + g] = bt;
      // ---- tail ----
      Nh = n;
      float psi = cA + bt;                      // psi[t] (fresh entry)
      bh = bt;
      Cm0 = Ak0 - bh; Cm1 = Ak1 - bh; Cm2 = Ak2 - bh; Cm3 = Ak3 - bh;
      // window shift for step t-1: slot s new = old slot s-1; fresh psi @ s=0
      float r0 = ror1(Q0),  r1 = ror1(Q1),  r2 = ror1(Q2),  r3 = ror1(Q3),
            r4 = ror1(Q4),  r5 = ror1(Q5),  r6 = ror1(Q6),  r7 = ror1(Q7),
            r8 = ror1(Q8),  r9 = ror1(Q9),  r10 = ror1(Q10), r11 = ror1(Q11),
            r12 = ror1(Q12);
      float q1 = ror9(Q0),  q2 = ror9(Q1),  q3 = ror9(Q2),  q4 = ror9(Q3),
            q5 = ror9(Q4),  q6 = ror9(Q5),  q7 = ror9(Q6),  q8 = ror9(Q7),
            q9 = ror9(Q8),  q10 = ror9(Q9), q11 = ror9(Q10), q12 = ror9(Q11);
      Q0  = l0 ? psi : r0;
      Q1  = l0 ? q1  : r1;   Q2  = l0 ? q2  : r2;
      Q3  = l0 ? q3  : r3;   Q4  = l0 ? q4  : r4;
      Q5  = l0 ? q5  : r5;   Q6  = l0 ? q6  : r6;
      Q7  = l0 ? q7  : r7;   Q8  = l0 ? q8  : r8;
      Q9  = l0 ? q9  : r9;   Q10 = l0 ? q10 : r10;
      Q11 = l0 ? q11 : r11;  Q12 = l0 ? q12 : r12;
      float mN = 0.f - Nh;
      float e0  = exp2_(Q0  + (LD[0]  + mN));
      float e1  = exp2_(Q1  + (LD[1]  + mN));
      float e2  = exp2_(Q2  + (LD[2]  + mN));
      float e3  = exp2_(Q3  + (LD[3]  + mN));
      float e4  = exp2_(Q4  + (LD[4]  + mN));
      float e5  = exp2_(Q5  + (LD[5]  + mN));
      float e6  = exp2_(Q6  + (LD[6]  + mN));
      float e7  = exp2_(Q7  + (LD[7]  + mN));
      float e8  = exp2_(Q8  + (LD[8]  + mN));
      float e9  = exp2_(Q9  + (LD[9]  + mN));
      float e10 = exp2_(Q10 + (LD[10] + mN));
      float e11 = exp2_(Q11 + (LD[11] + mN));
      float e12 = exp2_(Q12 + (LD[12] + mN));
      slocB = (((e0 + e1) + (e2 + e3)) + ((e4 + e5) + (e6 + e7))) +
              (((e8 + e9) + (e10 + e11)) + e12);
      cA = cB; cB = cC; cC = cN;
    }
  }
}

// out = softmax over k of (alpha2 + beta2), log2 domain (ratios identical)
__global__ __launch_bounds__(256) void softmax_kernel(
    float* __restrict__ ab, const float* __restrict__ beta)
{
  int t = blockIdx.x * 256 + threadIdx.x;
  float s[KK];
  float mx = -INFINITY;
  #pragma unroll
  for (int k = 0; k < KK; ++k) {
    s[k] = ab[(size_t)t * KK + k] + beta[(size_t)t * KK + k];
    mx = fmaxf(mx, s[k]);
  }
  float sum = 0.0f;
  #pragma unroll
  for (int k = 0; k < KK; ++k) { s[k] = exp2_(s[k] - mx); sum += s[k]; }
  float inv = 1.0f / sum;
  #pragma unroll
  for (int k = 0; k < KK; ++k) ab[(size_t)t * KK + k] = s[k] * inv;
}

extern "C" void kernel_launch(void* const* d_in, const int* in_sizes, int n_in,
                              void* d_out, int out_size, void* d_ws, size_t ws_size,
                              hipStream_t stream) {
  const float* em  = (const float*)d_in[0];   // (T,K)
  const float* qw  = (const float*)d_in[1];   // (T,)
  const float* lpi = (const float*)d_in[2];   // (K,)
  const float* lA  = (const float*)d_in[3];   // (K,K)
  const float* lD  = (const float*)d_in[4];   // (K,U)
  // d_in[5] transition_mask == 1-eye(K): applied analytically (j != k)

  float* out  = (float*)d_out;                 // alpha2, then softmax in place
  float* cum  = (float*)d_ws;                  // (T+1)*K floats
  float* beta = (float*)d_ws + (size_t)(TT + 1) * KK;  // T*K floats

  cumsum_kernel<<<KK, 256, 0, stream>>>(em, qw, cum);
  scan_kernel<<<2, 192, 0, stream>>>(em, lpi, lA, lD, cum, out, beta);
  softmax_kernel<<<TT / 256, 256, 0, stream>>>(out, beta);
}